// Round 2
// baseline (265.538 us; speedup 1.0000x reference)
//
#include <hip/hip_runtime.h>
#include <hip/hip_bf16.h>
#include <math.h>

#define Bv 8
#define Tv 32
#define Nv 500
#define Fin 64
#define Hv 128
#define Ev 8000
#define Kv 3
#define BT (Bv*Tv)      /* 256 */
#define ROWS (BT*Nv)    /* 128000 */
#define TP (Tv+2)       /* 34 LDS time rows (1 pad each side) */
#define KK (Kv*Hv)      /* 384: flattened conv K dim */
#define LDSROW 144      /* 288B row stride: bank shift 8 -> 4-way on b128 A-reads */

typedef __attribute__((ext_vector_type(8))) short s8v;   // 8 bf16 = 4 VGPRs
typedef __attribute__((ext_vector_type(4))) float f4v;   // MFMA acc

// branch-free erf (Abramowitz-Stegun 7.1.26, |err| <= 1.5e-7): rcp + 5 FMA + v_exp.
// Replaces libm erff (branchy, both paths execute under divergence).
__device__ __forceinline__ float gelu_exact(float v){
    float t  = v*0.70710678118654752440f;
    float ax = fabsf(t);
    float k  = __builtin_amdgcn_rcpf(fmaf(0.3275911f, ax, 1.0f));
    float p  = k*fmaf(k, fmaf(k, fmaf(k, fmaf(k, 1.061405429f, -1.453152027f),
                                      1.421413741f), -0.284496736f), 0.254829592f);
    float e  = __expf(-ax*ax);
    float er = fmaf(-p, e, 1.0f);           // erf(|t|)
    er = copysignf(er, t);
    return 0.5f*v*(1.0f + er);
}
__device__ __forceinline__ short f2bs(float f){
    union { __hip_bfloat16 h; short s; } u;
    u.h = __float2bfloat16(f);
    return u.s;
}
__device__ __forceinline__ float b2f(short s){
    union { unsigned int i; float f; } u;
    u.i = ((unsigned int)(unsigned short)s) << 16;
    return u.f;
}

// ---- fused: block 0 = graph prep (degree+counts, scan, CSR fill);
//      blocks [1, 2000] = x transpose to bf16; tail 64 blocks = weight prep.
//      prep is independent of xpose, so it overlaps instead of serializing. ----
__global__ __launch_bounds__(1024) void k_xprep(const float* __restrict__ x,
        short* __restrict__ X2b, const float* __restrict__ W,
        const float* __restrict__ Wg, const float* __restrict__ Wr,
        short* __restrict__ W2, short* __restrict__ Wgt, short* __restrict__ Wrt,
        const int* __restrict__ ei, const float* __restrict__ ew,
        float* __restrict__ dinv, int* __restrict__ offs,
        int* __restrict__ csrc, float* __restrict__ cw){
    __shared__ float sdeg[Nv];
    __shared__ int   scnt[Nv];
    __shared__ float sdv[Nv];
    __shared__ int   scur[Nv];
    __shared__ int   sa[512], sb[512];
    int bid = blockIdx.x;
    int tid = threadIdx.x;
    if (bid == 0){
        // ---- graph prep (1024 threads) ----
        if (tid < Nv){ sdeg[tid] = 1.0f; scnt[tid] = 0; }   // self-loop pre-added
        __syncthreads();
        for (int e = tid; e < Ev; e += 1024){
            int d = ei[Ev + e];
            atomicAdd(&sdeg[d], ew[e]);
            atomicAdd(&scnt[d], 1);
        }
        __syncthreads();
        int c = 0;
        if (tid < Nv){
            float d = sdeg[tid];
            float v = (d > 0.f) ? rsqrtf(d) : 0.f;
            sdv[tid] = v; dinv[tid] = v;
        }
        if (tid < 512){ c = (tid < Nv) ? scnt[tid] : 0; sa[tid] = c; }
        __syncthreads();
        int* s = sa; int* t = sb;
        for (int off = 1; off < 512; off <<= 1){
            int v = 0;
            if (tid < 512){ v = s[tid]; if (tid >= off) v += s[tid - off]; }
            if (tid < 512) t[tid] = v;
            __syncthreads();
            int* tmp = s; s = t; t = tmp;
        }
        if (tid < Nv){ int excl = s[tid] - c; offs[tid] = excl; scur[tid] = excl; }
        if (tid == 0) offs[Nv] = Ev;
        __syncthreads();
        for (int e = tid; e < Ev; e += 1024){
            int sn = ei[e], d = ei[Ev + e];
            int pos = atomicAdd(&scur[d], 1);
            csrc[pos] = sn;
            cw[pos] = sdv[sn]*ew[e]*sdv[d];
        }
    } else if (bid <= ROWS/64){
        // ---- x (bt,n,c) fp32 -> X2b (n, bt*64+c) bf16 ----
        int gid = (bid-1)*1024 + tid;        // one float4; total ROWS*16
        int row = gid >> 4, c4 = gid & 15;
        int bt = row / Nv;
        int n  = row - bt*Nv;
        float4 v = ((const float4*)x)[gid];
        short4 sv;
        sv.x = f2bs(v.x); sv.y = f2bs(v.y); sv.z = f2bs(v.z); sv.w = f2bs(v.w);
        *(short4*)(X2b + (size_t)n*(BT*64) + bt*64 + c4*4) = sv;
    } else {
        int idx = (bid - 1 - ROWS/64)*1024 + tid;
        if (idx < Hv*Hv*Kv){
            int o = idx/(Hv*Kv);
            int rem = idx - o*(Hv*Kv);
            int i = rem/Kv, k = rem - i*Kv;
            W2[o*KK + k*Hv + i] = f2bs(W[idx]);           // W2[o][k*128+i]
        } else if (idx < Hv*Hv*Kv + Hv*64){
            int j = idx - Hv*Hv*Kv;
            int o = j >> 6, k = j & 63;
            Wgt[j] = f2bs(Wg[k*Hv + o]);                  // Wgt[o][k]
        } else if (idx < Hv*Hv*Kv + 2*Hv*64){
            int j = idx - Hv*Hv*Kv - Hv*64;
            int o = j >> 6, k = j & 63;
            Wrt[j] = f2bs(Wr[k*Hv + o]);                  // Wrt[o][k]
        }
    }
}

// ---- dense-row SpMM: AGG2[n, btc] = dv^2*X2b[n] + sum_e w_e * X2b[src_e] ----
// XCD-stripe swizzle: ct = bid&7 pins one 2MB column stripe per XCD (round-robin
// dispatch) -> gather becomes per-XCD L2-resident instead of LLC traffic.
__global__ __launch_bounds__(256) void k_spmm(const short* __restrict__ X2b,
        const float* __restrict__ dinv, const int* __restrict__ offs,
        const int* __restrict__ csrc, const float* __restrict__ cw,
        short* __restrict__ AGG2){
    int bid = blockIdx.x;
    int ct = bid & 7;
    int n  = bid >> 3;
    int col = ct*2048 + threadIdx.x*8;
    float dv = dinv[n];
    float sw = dv*dv;
    float acc[8];
    s8v v = *(const s8v*)(X2b + (size_t)n*(BT*64) + col);
    #pragma unroll
    for (int q = 0; q < 8; ++q) acc[q] = sw * b2f(v[q]);
    int e0 = offs[n], e1 = offs[n+1];
    for (int e = e0; e < e1; ++e){
        int s = csrc[e]; float w = cw[e];
        s8v u = *(const s8v*)(X2b + (size_t)s*(BT*64) + col);
        #pragma unroll
        for (int q = 0; q < 8; ++q) acc[q] = fmaf(w, b2f(u[q]), acc[q]);
    }
    s8v r;
    #pragma unroll
    for (int q = 0; q < 8; ++q) r[q] = f2bs(acc[q]);
    *(s8v*)(AGG2 + (size_t)n*(BT*64) + col) = r;
}

// ---- mega kernel: GCN GEMM (K=64) -> GELU -> LDS; residual GEMM (K=64);
//      temporal conv GEMM (K=384); bias+GELU+residual+LayerNorm -> out ----
// block = 4 waves, 4 nodes; wave w owns output channels [w*32, w*32+32).
// launch_bounds(256,4): LDS 40448*4 = 161792 <= 163840 -> 4 blocks/CU fit.
__global__ __launch_bounds__(256, 4) void k_mega(
        const short* __restrict__ AGG2, const short* __restrict__ X2b,
        const short* __restrict__ W2, const short* __restrict__ Wgt,
        const short* __restrict__ Wrt,
        const float* __restrict__ bg, const float* __restrict__ btm,
        const float* __restrict__ br, const float* __restrict__ lw,
        const float* __restrict__ lb, float* __restrict__ out){
    __shared__ short hs[4*TP*LDSROW];      // 39168 B
    __shared__ float red[Tv][4][2];
    int tid  = threadIdx.x;
    int w    = tid >> 6;
    int lane = tid & 63;
    int quad = lane >> 4;
    int laneo = lane & 15;
    int bid = blockIdx.x;
    int b  = bid / 125;
    int n0 = (bid - b*125) * 4;
    int o_base = w*32;

    float bgv[2], bbv[2], brv[2], lwv[2], lbv[2];
    #pragma unroll
    for (int nt = 0; nt < 2; ++nt){
        int o = o_base + nt*16 + laneo;
        bgv[nt] = bg[o]; bbv[nt] = btm[o]; brv[nt] = br[o];
        lwv[nt] = lw[o]; lbv[nt] = lb[o];
    }

    // GCN B fragments (K=64: 2 k-steps)
    s8v bwg[2][2];
    #pragma unroll
    for (int nt = 0; nt < 2; ++nt){
        const short* wp = Wgt + (o_base + nt*16 + laneo)*64 + quad*8;
        bwg[nt][0] = *(const s8v*)wp;
        bwg[nt][1] = *(const s8v*)(wp + 32);
    }

    // zero the pad rows (tp=0, tp=33) of all 4 nodes
    if (tid < 128){
        int node = tid >> 5, rem = tid & 31;
        int tp = (rem >> 4)*(TP-1), c8 = rem & 15;
        s8v z = {0,0,0,0,0,0,0,0};
        *(s8v*)&hs[node*(TP*LDSROW) + tp*LDSROW + c8*8] = z;
    }

    // ---- stage: GCN GEMM per node, GELU, write h to LDS (A-layout rows) ----
    for (int g = 0; g < 4; ++g){
        int n = n0 + g;
        const short* ap = AGG2 + ((size_t)n*BT + b*Tv)*64;
        #pragma unroll
        for (int m = 0; m < 2; ++m){
            const short* arp = ap + (m*16 + laneo)*64 + quad*8;
            s8v a0 = *(const s8v*)arp;
            s8v a1 = *(const s8v*)(arp + 32);
            f4v h0 = {0.f,0.f,0.f,0.f}, h1 = {0.f,0.f,0.f,0.f};
            h0 = __builtin_amdgcn_mfma_f32_16x16x32_bf16(a0, bwg[0][0], h0, 0,0,0);
            h0 = __builtin_amdgcn_mfma_f32_16x16x32_bf16(a1, bwg[0][1], h0, 0,0,0);
            h1 = __builtin_amdgcn_mfma_f32_16x16x32_bf16(a0, bwg[1][0], h1, 0,0,0);
            h1 = __builtin_amdgcn_mfma_f32_16x16x32_bf16(a1, bwg[1][1], h1, 0,0,0);
            #pragma unroll
            for (int r = 0; r < 4; ++r){
                int tp = m*16 + quad*4 + r + 1;     // C layout: row=quad*4+r
                short* hrow = &hs[g*(TP*LDSROW) + tp*LDSROW];
                hrow[o_base + laneo]      = f2bs(gelu_exact(h0[r] + bgv[0]));
                hrow[o_base + 16 + laneo] = f2bs(gelu_exact(h1[r] + bgv[1]));
            }
        }
    }

    // conv + residual B fragments (loaded late to cut peak VGPR in stage phase)
    s8v breg[2][12], bwr[2][2];
    #pragma unroll
    for (int nt = 0; nt < 2; ++nt){
        int o = o_base + nt*16 + laneo;
        const short* wp = W2 + o*KK + quad*8;
        #pragma unroll
        for (int s = 0; s < 12; ++s)
            breg[nt][s] = *(const s8v*)(wp + s*32);
        const short* wr = Wrt + o*64 + quad*8;
        bwr[nt][0] = *(const s8v*)wr;
        bwr[nt][1] = *(const s8v*)(wr + 32);
    }
    __syncthreads();

    for (int g = 0; g < 4; ++g){
        int n = n0 + g;
        // ---- temporal conv MFMA: 2 m-tiles x 12 K-steps x 2 n-tiles ----
        f4v acc[2][2];
        #pragma unroll
        for (int m = 0; m < 2; ++m)
            #pragma unroll
            for (int nt = 0; nt < 2; ++nt)
                acc[m][nt] = (f4v){0.f,0.f,0.f,0.f};
        #pragma unroll
        for (int m = 0; m < 2; ++m){
            #pragma unroll
            for (int s = 0; s < 12; ++s){
                int k  = s >> 2;
                int i0 = (s & 3) * 32;
                int tp = m*16 + laneo + k;
                s8v a = *(const s8v*)&hs[g*(TP*LDSROW) + tp*LDSROW + i0 + quad*8];
                acc[m][0] = __builtin_amdgcn_mfma_f32_16x16x32_bf16(a, breg[0][s], acc[m][0], 0,0,0);
                acc[m][1] = __builtin_amdgcn_mfma_f32_16x16x32_bf16(a, breg[1][s], acc[m][1], 0,0,0);
            }
        }
        // ---- residual GEMM from X2b window (same C layout -> register add) ----
        f4v racc[2][2];
        #pragma unroll
        for (int m = 0; m < 2; ++m)
            #pragma unroll
            for (int nt = 0; nt < 2; ++nt)
                racc[m][nt] = (f4v){0.f,0.f,0.f,0.f};
        const short* xp = X2b + ((size_t)n*BT + b*Tv)*64;
        #pragma unroll
        for (int m = 0; m < 2; ++m){
            const short* xrp = xp + (m*16 + laneo)*64 + quad*8;
            s8v a0 = *(const s8v*)xrp;
            s8v a1 = *(const s8v*)(xrp + 32);
            racc[m][0] = __builtin_amdgcn_mfma_f32_16x16x32_bf16(a0, bwr[0][0], racc[m][0], 0,0,0);
            racc[m][0] = __builtin_amdgcn_mfma_f32_16x16x32_bf16(a1, bwr[0][1], racc[m][0], 0,0,0);
            racc[m][1] = __builtin_amdgcn_mfma_f32_16x16x32_bf16(a0, bwr[1][0], racc[m][1], 0,0,0);
            racc[m][1] = __builtin_amdgcn_mfma_f32_16x16x32_bf16(a1, bwr[1][1], racc[m][1], 0,0,0);
        }
        // ---- epilogue: bias+GELU+residual, LN stats ----
        size_t obase = ((size_t)b*Tv*Nv + n)*Hv;
        float yv[2][2][4];
        float srow[2][4], ssrow[2][4];
        #pragma unroll
        for (int m = 0; m < 2; ++m)
            #pragma unroll
            for (int r = 0; r < 4; ++r){ srow[m][r] = 0.f; ssrow[m][r] = 0.f; }
        #pragma unroll
        for (int m = 0; m < 2; ++m){
            #pragma unroll
            for (int nt = 0; nt < 2; ++nt){
                #pragma unroll
                for (int r = 0; r < 4; ++r){
                    float gv = gelu_exact(acc[m][nt][r] + bbv[nt]);
                    float y = gv + racc[m][nt][r] + brv[nt];
                    yv[m][nt][r] = y;
                    srow[m][r] += y; ssrow[m][r] += y*y;
                }
            }
        }
        #pragma unroll
        for (int m = 0; m < 2; ++m)
            #pragma unroll
            for (int r = 0; r < 4; ++r){
                #pragma unroll
                for (int msk = 8; msk >= 1; msk >>= 1){
                    srow[m][r]  += __shfl_xor(srow[m][r],  msk, 64);
                    ssrow[m][r] += __shfl_xor(ssrow[m][r], msk, 64);
                }
            }
        if (laneo == 0){
            #pragma unroll
            for (int m = 0; m < 2; ++m)
                #pragma unroll
                for (int r = 0; r < 4; ++r){
                    int t = m*16 + quad*4 + r;
                    red[t][w][0] = srow[m][r];
                    red[t][w][1] = ssrow[m][r];
                }
        }
        __syncthreads();
        #pragma unroll
        for (int m = 0; m < 2; ++m){
            #pragma unroll
            for (int r = 0; r < 4; ++r){
                int t = m*16 + quad*4 + r;
                float s  = red[t][0][0] + red[t][1][0] + red[t][2][0] + red[t][3][0];
                float ss = red[t][0][1] + red[t][1][1] + red[t][2][1] + red[t][3][1];
                float mu = s * (1.f/128.f);
                float var = fmaxf(ss * (1.f/128.f) - mu*mu, 0.f);
                float rstd = rsqrtf(var + 1e-5f);
                #pragma unroll
                for (int nt = 0; nt < 2; ++nt){
                    int o = o_base + nt*16 + laneo;
                    out[obase + (size_t)t*Nv*Hv + o] =
                        (yv[m][nt][r] - mu)*rstd*lwv[nt] + lbv[nt];
                }
            }
        }
        __syncthreads();
    }
}

extern "C" void kernel_launch(void* const* d_in, const int* in_sizes, int n_in,
                              void* d_out, int out_size, void* d_ws, size_t ws_size,
                              hipStream_t stream){
    const float* x   = (const float*)d_in[0];
    const int*   ei  = (const int*)d_in[1];
    const float* ew  = (const float*)d_in[2];
    const float* Wg  = (const float*)d_in[3];
    const float* bg  = (const float*)d_in[4];
    const float* Wtm = (const float*)d_in[5];
    const float* btm = (const float*)d_in[6];
    const float* lw  = (const float*)d_in[7];
    const float* lb  = (const float*)d_in[8];
    const float* Wr  = (const float*)d_in[9];
    const float* br  = (const float*)d_in[10];
    float* out = (float*)d_out;

    char* ws = (char*)d_ws;
    float* dinv = (float*)(ws + 0);            // 2048 B
    int*   offs = (int*)  (ws + 4096);         // 2048 B
    int*   csrc = (int*)  (ws + 8192);         // 32768 B
    float* cwn  = (float*)(ws + 40960);        // 32768 B
    short* W2   = (short*)(ws + 73728);        // 98304 B
    short* Wgt  = (short*)(ws + 172032);       // 16384 B
    short* Wrt  = (short*)(ws + 188416);       // 16384 B
    short* X2b  = (short*)(ws + 204800);       // 16.384 MB
    short* AGG2 = (short*)(ws + 16588800);     // 16.384 MB

    k_xprep<<<1 + ROWS/64 + 64, 1024, 0, stream>>>(x, X2b, Wtm, Wg, Wr,
                                                   W2, Wgt, Wrt,
                                                   ei, ew, dinv, offs, csrc, cwn);
    k_spmm <<<8*Nv, 256, 0, stream>>>(X2b, dinv, offs, csrc, cwn, AGG2);
    k_mega <<<(Bv*Nv)/4, 256, 0, stream>>>(AGG2, X2b, W2, Wgt, Wrt,
                                           bg, btm, br, lw, lb, out);
}

// Round 3
// 214.768 us; speedup vs baseline: 1.2364x; 1.2364x over previous
//
#include <hip/hip_runtime.h>
#include <hip/hip_bf16.h>
#include <math.h>

#define Bv 8
#define Tv 32
#define Nv 500
#define Fin 64
#define Hv 128
#define Ev 8000
#define Kv 3
#define BT (Bv*Tv)      /* 256 */
#define ROWS (BT*Nv)    /* 128000 */
#define TP (Tv+2)       /* 34 LDS time rows (1 pad each side) */
#define KK (Kv*Hv)      /* 384: flattened conv K dim */
#define LDSROW 144      /* 288B row stride: bank shift 8 -> 4-way on b128 A-reads */
#define AGROW 72        /* 144B AGG-window row stride: 2-way conflict on A-reads */

typedef __attribute__((ext_vector_type(8))) short s8v;   // 8 bf16 = 4 VGPRs
typedef __attribute__((ext_vector_type(4))) float f4v;   // MFMA acc

// branch-free erf (Abramowitz-Stegun 7.1.26, |err| <= 1.5e-7): rcp + 5 FMA + v_exp.
__device__ __forceinline__ float gelu_exact(float v){
    float t  = v*0.70710678118654752440f;
    float ax = fabsf(t);
    float k  = __builtin_amdgcn_rcpf(fmaf(0.3275911f, ax, 1.0f));
    float p  = k*fmaf(k, fmaf(k, fmaf(k, fmaf(k, 1.061405429f, -1.453152027f),
                                      1.421413741f), -0.284496736f), 0.254829592f);
    float e  = __expf(-ax*ax);
    float er = fmaf(-p, e, 1.0f);           // erf(|t|)
    er = copysignf(er, t);
    return 0.5f*v*(1.0f + er);
}
__device__ __forceinline__ short f2bs(float f){
    union { __hip_bfloat16 h; short s; } u;
    u.h = __float2bfloat16(f);
    return u.s;
}
__device__ __forceinline__ float b2f(short s){
    union { unsigned int i; float f; } u;
    u.i = ((unsigned int)(unsigned short)s) << 16;
    return u.f;
}

// ---- fused: block 0 = graph prep (degree+counts, scan, CSR fill);
//      blocks [1, 2000] = x transpose to bf16; tail 64 blocks = weight prep. ----
__global__ __launch_bounds__(1024) void k_xprep(const float* __restrict__ x,
        short* __restrict__ X2b, const float* __restrict__ W,
        const float* __restrict__ Wg, const float* __restrict__ Wr,
        short* __restrict__ W2, short* __restrict__ Wgt, short* __restrict__ Wrt,
        const int* __restrict__ ei, const float* __restrict__ ew,
        float* __restrict__ dinv, int* __restrict__ offs,
        int* __restrict__ csrc, float* __restrict__ cw){
    __shared__ float sdeg[Nv];
    __shared__ int   scnt[Nv];
    __shared__ float sdv[Nv];
    __shared__ int   scur[Nv];
    __shared__ int   sa[512], sb[512];
    int bid = blockIdx.x;
    int tid = threadIdx.x;
    if (bid == 0){
        // ---- graph prep (1024 threads) ----
        if (tid < Nv){ sdeg[tid] = 1.0f; scnt[tid] = 0; }   // self-loop pre-added
        __syncthreads();
        for (int e = tid; e < Ev; e += 1024){
            int d = ei[Ev + e];
            atomicAdd(&sdeg[d], ew[e]);
            atomicAdd(&scnt[d], 1);
        }
        __syncthreads();
        int c = 0;
        if (tid < Nv){
            float d = sdeg[tid];
            float v = (d > 0.f) ? rsqrtf(d) : 0.f;
            sdv[tid] = v; dinv[tid] = v;
        }
        if (tid < 512){ c = (tid < Nv) ? scnt[tid] : 0; sa[tid] = c; }
        __syncthreads();
        int* s = sa; int* t = sb;
        for (int off = 1; off < 512; off <<= 1){
            int v = 0;
            if (tid < 512){ v = s[tid]; if (tid >= off) v += s[tid - off]; }
            if (tid < 512) t[tid] = v;
            __syncthreads();
            int* tmp = s; s = t; t = tmp;
        }
        if (tid < Nv){ int excl = s[tid] - c; offs[tid] = excl; scur[tid] = excl; }
        if (tid == 0) offs[Nv] = Ev;
        __syncthreads();
        for (int e = tid; e < Ev; e += 1024){
            int sn = ei[e], d = ei[Ev + e];
            int pos = atomicAdd(&scur[d], 1);
            csrc[pos] = sn;
            cw[pos] = sdv[sn]*ew[e]*sdv[d];
        }
    } else if (bid <= ROWS/64){
        // ---- x (bt,n,c) fp32 -> X2b (n, bt*64+c) bf16 ----
        int gid = (bid-1)*1024 + tid;        // one float4; total ROWS*16
        int row = gid >> 4, c4 = gid & 15;
        int bt = row / Nv;
        int n  = row - bt*Nv;
        float4 v = ((const float4*)x)[gid];
        short4 sv;
        sv.x = f2bs(v.x); sv.y = f2bs(v.y); sv.z = f2bs(v.z); sv.w = f2bs(v.w);
        *(short4*)(X2b + (size_t)n*(BT*64) + bt*64 + c4*4) = sv;
    } else {
        int idx = (bid - 1 - ROWS/64)*1024 + tid;
        if (idx < Hv*Hv*Kv){
            int o = idx/(Hv*Kv);
            int rem = idx - o*(Hv*Kv);
            int i = rem/Kv, k = rem - i*Kv;
            W2[o*KK + k*Hv + i] = f2bs(W[idx]);           // W2[o][k*128+i]
        } else if (idx < Hv*Hv*Kv + Hv*64){
            int j = idx - Hv*Hv*Kv;
            int o = j >> 6, k = j & 63;
            Wgt[j] = f2bs(Wg[k*Hv + o]);                  // Wgt[o][k]
        } else if (idx < Hv*Hv*Kv + 2*Hv*64){
            int j = idx - Hv*Hv*Kv - Hv*64;
            int o = j >> 6, k = j & 63;
            Wrt[j] = f2bs(Wr[k*Hv + o]);                  // Wrt[o][k]
        }
    }
}

// ---- mega kernel (now with fused SpMM):
//   phase A: dense-row SpMM for 4 nodes' (32t x 64c) windows -> LDS (ags)
//   stage:   GCN GEMM (K=64) -> GELU -> LDS (hs)
//   main:    temporal conv GEMM (K=384) + residual GEMM (K=64)
//            + bias+GELU+residual+LayerNorm -> out
// block = 4 waves, 4 nodes; wave w owns output channels [w*32, w*32+32).
// bid swizzle: b = bid&7 pins one 2MB X2b column stripe per XCD (round-robin
// dispatch) -> SpMM gather is per-XCD L2-resident. 125*8 = 1000, bijective.
__global__ __launch_bounds__(256, 2) void k_mega(
        const short* __restrict__ X2b,
        const float* __restrict__ dinv, const int* __restrict__ offs,
        const int* __restrict__ csrc, const float* __restrict__ cw,
        const short* __restrict__ W2, const short* __restrict__ Wgt,
        const short* __restrict__ Wrt,
        const float* __restrict__ bg, const float* __restrict__ btm,
        const float* __restrict__ br, const float* __restrict__ lw,
        const float* __restrict__ lb, float* __restrict__ out){
    __shared__ short hs[4*TP*LDSROW];      // 39168 B
    __shared__ short ags[4*Tv*AGROW];      // 18432 B: per-node AGG window
    __shared__ float red[Tv][4][2];
    int tid  = threadIdx.x;
    int w    = tid >> 6;
    int lane = tid & 63;
    int quad = lane >> 4;
    int laneo = lane & 15;
    int bid = blockIdx.x;
    int b  = bid & 7;
    int n0 = (bid >> 3) * 4;
    int o_base = w*32;

    float bgv[2], bbv[2], brv[2], lwv[2], lbv[2];
    #pragma unroll
    for (int nt = 0; nt < 2; ++nt){
        int o = o_base + nt*16 + laneo;
        bgv[nt] = bg[o]; bbv[nt] = btm[o]; brv[nt] = br[o];
        lwv[nt] = lw[o]; lbv[nt] = lb[o];
    }

    // GCN B fragments (K=64: 2 k-steps)
    s8v bwg[2][2];
    #pragma unroll
    for (int nt = 0; nt < 2; ++nt){
        const short* wp = Wgt + (o_base + nt*16 + laneo)*64 + quad*8;
        bwg[nt][0] = *(const s8v*)wp;
        bwg[nt][1] = *(const s8v*)(wp + 32);
    }

    // zero the pad rows (tp=0, tp=33) of all 4 nodes
    if (tid < 128){
        int node = tid >> 5, rem = tid & 31;
        int tp = (rem >> 4)*(TP-1), c8 = rem & 15;
        s8v z = {0,0,0,0,0,0,0,0};
        *(s8v*)&hs[node*(TP*LDSROW) + tp*LDSROW + c8*8] = z;
    }

    // ---- phase A: fused SpMM. Thread t covers 8 shorts of the contiguous
    //      4KB window X2b[n*16384 + b*2048 + t*8]; gathers are fully coalesced
    //      (1KB/wave) and L2-resident within the XCD's b-stripe. ----
    {
        int r  = tid >> 3;          // t-row 0..31
        int c8 = tid & 7;           // col chunk 0..7
        int woff = b*2048 + tid*8;
        for (int g = 0; g < 4; ++g){
            int n = n0 + g;
            float dv = dinv[n];
            float sw = dv*dv;
            float acc[8];
            s8v v = *(const s8v*)(X2b + (size_t)n*(BT*64) + woff);
            #pragma unroll
            for (int q = 0; q < 8; ++q) acc[q] = sw * b2f(v[q]);
            int e0 = offs[n], e1 = offs[n+1];
            for (int e = e0; e < e1; ++e){
                int s = csrc[e]; float we = cw[e];
                s8v u = *(const s8v*)(X2b + (size_t)s*(BT*64) + woff);
                #pragma unroll
                for (int q = 0; q < 8; ++q) acc[q] = fmaf(we, b2f(u[q]), acc[q]);
            }
            s8v rr;
            #pragma unroll
            for (int q = 0; q < 8; ++q) rr[q] = f2bs(acc[q]);
            *(s8v*)&ags[g*(Tv*AGROW) + r*AGROW + c8*8] = rr;
        }
    }
    __syncthreads();

    // ---- stage: GCN GEMM per node from ags, GELU, write h to LDS ----
    for (int g = 0; g < 4; ++g){
        const short* ap = &ags[g*(Tv*AGROW)];
        #pragma unroll
        for (int m = 0; m < 2; ++m){
            const short* arp = ap + (m*16 + laneo)*AGROW + quad*8;
            s8v a0 = *(const s8v*)arp;
            s8v a1 = *(const s8v*)(arp + 32);
            f4v h0 = {0.f,0.f,0.f,0.f}, h1 = {0.f,0.f,0.f,0.f};
            h0 = __builtin_amdgcn_mfma_f32_16x16x32_bf16(a0, bwg[0][0], h0, 0,0,0);
            h0 = __builtin_amdgcn_mfma_f32_16x16x32_bf16(a1, bwg[0][1], h0, 0,0,0);
            h1 = __builtin_amdgcn_mfma_f32_16x16x32_bf16(a0, bwg[1][0], h1, 0,0,0);
            h1 = __builtin_amdgcn_mfma_f32_16x16x32_bf16(a1, bwg[1][1], h1, 0,0,0);
            #pragma unroll
            for (int r = 0; r < 4; ++r){
                int tp = m*16 + quad*4 + r + 1;     // C layout: row=quad*4+r
                short* hrow = &hs[g*(TP*LDSROW) + tp*LDSROW];
                hrow[o_base + laneo]      = f2bs(gelu_exact(h0[r] + bgv[0]));
                hrow[o_base + 16 + laneo] = f2bs(gelu_exact(h1[r] + bgv[1]));
            }
        }
    }

    // conv + residual B fragments (loaded late to cut peak VGPR in stage phase)
    s8v breg[2][12], bwr[2][2];
    #pragma unroll
    for (int nt = 0; nt < 2; ++nt){
        int o = o_base + nt*16 + laneo;
        const short* wp = W2 + o*KK + quad*8;
        #pragma unroll
        for (int s = 0; s < 12; ++s)
            breg[nt][s] = *(const s8v*)(wp + s*32);
        const short* wr = Wrt + o*64 + quad*8;
        bwr[nt][0] = *(const s8v*)wr;
        bwr[nt][1] = *(const s8v*)(wr + 32);
    }
    __syncthreads();

    for (int g = 0; g < 4; ++g){
        int n = n0 + g;
        // ---- temporal conv MFMA: 2 m-tiles x 12 K-steps x 2 n-tiles ----
        f4v acc[2][2];
        #pragma unroll
        for (int m = 0; m < 2; ++m)
            #pragma unroll
            for (int nt = 0; nt < 2; ++nt)
                acc[m][nt] = (f4v){0.f,0.f,0.f,0.f};
        #pragma unroll
        for (int m = 0; m < 2; ++m){
            #pragma unroll
            for (int s = 0; s < 12; ++s){
                int k  = s >> 2;
                int i0 = (s & 3) * 32;
                int tp = m*16 + laneo + k;
                s8v a = *(const s8v*)&hs[g*(TP*LDSROW) + tp*LDSROW + i0 + quad*8];
                acc[m][0] = __builtin_amdgcn_mfma_f32_16x16x32_bf16(a, breg[0][s], acc[m][0], 0,0,0);
                acc[m][1] = __builtin_amdgcn_mfma_f32_16x16x32_bf16(a, breg[1][s], acc[m][1], 0,0,0);
            }
        }
        // ---- residual GEMM from X2b window (same C layout -> register add) ----
        f4v racc[2][2];
        #pragma unroll
        for (int m = 0; m < 2; ++m)
            #pragma unroll
            for (int nt = 0; nt < 2; ++nt)
                racc[m][nt] = (f4v){0.f,0.f,0.f,0.f};
        const short* xp = X2b + ((size_t)n*BT + b*Tv)*64;
        #pragma unroll
        for (int m = 0; m < 2; ++m){
            const short* xrp = xp + (m*16 + laneo)*64 + quad*8;
            s8v a0 = *(const s8v*)xrp;
            s8v a1 = *(const s8v*)(xrp + 32);
            racc[m][0] = __builtin_amdgcn_mfma_f32_16x16x32_bf16(a0, bwr[0][0], racc[m][0], 0,0,0);
            racc[m][0] = __builtin_amdgcn_mfma_f32_16x16x32_bf16(a1, bwr[0][1], racc[m][0], 0,0,0);
            racc[m][1] = __builtin_amdgcn_mfma_f32_16x16x32_bf16(a0, bwr[1][0], racc[m][1], 0,0,0);
            racc[m][1] = __builtin_amdgcn_mfma_f32_16x16x32_bf16(a1, bwr[1][1], racc[m][1], 0,0,0);
        }
        // ---- epilogue: bias+GELU+residual, LN stats ----
        size_t obase = ((size_t)b*Tv*Nv + n)*Hv;
        float yv[2][2][4];
        float srow[2][4], ssrow[2][4];
        #pragma unroll
        for (int m = 0; m < 2; ++m)
            #pragma unroll
            for (int r = 0; r < 4; ++r){ srow[m][r] = 0.f; ssrow[m][r] = 0.f; }
        #pragma unroll
        for (int m = 0; m < 2; ++m){
            #pragma unroll
            for (int nt = 0; nt < 2; ++nt){
                #pragma unroll
                for (int r = 0; r < 4; ++r){
                    float gv = gelu_exact(acc[m][nt][r] + bbv[nt]);
                    float y = gv + racc[m][nt][r] + brv[nt];
                    yv[m][nt][r] = y;
                    srow[m][r] += y; ssrow[m][r] += y*y;
                }
            }
        }
        #pragma unroll
        for (int m = 0; m < 2; ++m)
            #pragma unroll
            for (int r = 0; r < 4; ++r){
                #pragma unroll
                for (int msk = 8; msk >= 1; msk >>= 1){
                    srow[m][r]  += __shfl_xor(srow[m][r],  msk, 64);
                    ssrow[m][r] += __shfl_xor(ssrow[m][r], msk, 64);
                }
            }
        if (laneo == 0){
            #pragma unroll
            for (int m = 0; m < 2; ++m)
                #pragma unroll
                for (int r = 0; r < 4; ++r){
                    int t = m*16 + quad*4 + r;
                    red[t][w][0] = srow[m][r];
                    red[t][w][1] = ssrow[m][r];
                }
        }
        __syncthreads();
        #pragma unroll
        for (int m = 0; m < 2; ++m){
            #pragma unroll
            for (int r = 0; r < 4; ++r){
                int t = m*16 + quad*4 + r;
                float s  = red[t][0][0] + red[t][1][0] + red[t][2][0] + red[t][3][0];
                float ss = red[t][0][1] + red[t][1][1] + red[t][2][1] + red[t][3][1];
                float mu = s * (1.f/128.f);
                float var = fmaxf(ss * (1.f/128.f) - mu*mu, 0.f);
                float rstd = rsqrtf(var + 1e-5f);
                #pragma unroll
                for (int nt = 0; nt < 2; ++nt){
                    int o = o_base + nt*16 + laneo;
                    out[obase + (size_t)t*Nv*Hv + o] =
                        (yv[m][nt][r] - mu)*rstd*lwv[nt] + lbv[nt];
                }
            }
        }
        __syncthreads();
    }
}

extern "C" void kernel_launch(void* const* d_in, const int* in_sizes, int n_in,
                              void* d_out, int out_size, void* d_ws, size_t ws_size,
                              hipStream_t stream){
    const float* x   = (const float*)d_in[0];
    const int*   ei  = (const int*)d_in[1];
    const float* ew  = (const float*)d_in[2];
    const float* Wg  = (const float*)d_in[3];
    const float* bg  = (const float*)d_in[4];
    const float* Wtm = (const float*)d_in[5];
    const float* btm = (const float*)d_in[6];
    const float* lw  = (const float*)d_in[7];
    const float* lb  = (const float*)d_in[8];
    const float* Wr  = (const float*)d_in[9];
    const float* br  = (const float*)d_in[10];
    float* out = (float*)d_out;

    char* ws = (char*)d_ws;
    float* dinv = (float*)(ws + 0);            // 2048 B
    int*   offs = (int*)  (ws + 4096);         // 2048 B
    int*   csrc = (int*)  (ws + 8192);         // 32768 B
    float* cwn  = (float*)(ws + 40960);        // 32768 B
    short* W2   = (short*)(ws + 73728);        // 98304 B
    short* Wgt  = (short*)(ws + 172032);       // 16384 B
    short* Wrt  = (short*)(ws + 188416);       // 16384 B
    short* X2b  = (short*)(ws + 204800);       // 16.384 MB

    k_xprep<<<1 + ROWS/64 + 64, 1024, 0, stream>>>(x, X2b, Wtm, Wg, Wr,
                                                   W2, Wgt, Wrt,
                                                   ei, ew, dinv, offs, csrc, cwn);
    k_mega <<<(Bv*Nv)/4, 256, 0, stream>>>(X2b, dinv, offs, csrc, cwn,
                                           W2, Wgt, Wrt,
                                           bg, btm, br, lw, lb, out);
}